// Round 1
// baseline (656.254 us; speedup 1.0000x reference)
//
#include <hip/hip_runtime.h>

// Problem constants (B=8, S=256, F=16384, K=32)
#define N_ELEMS  33554432   // 8*256*16384
#define N4       8388608    // N_ELEMS/4
#define N_TOKENS 2048
#define F4       4096       // float4 per token
#define K_TOTAL  65536u     // K * B * S
#define NBINS    4096       // fine bins over key range [0xC0000000, 0xC1000000) == f in [2,8)

// ws layout (uint32 word indices)
#define C_NG       4096     // gated-list counter
#define C_WINTH    4097     // winner threshold (key >= -> definitely selected)
#define C_CANDTH   4098     // candidate threshold (cutoff-bin lower edge)
#define C_NEED     4099     // how many to take from the cutoff bin
#define C_FB       4100     // fallback flag
#define C_N2       4101     // cutoff-bin candidate counter
#define C_BAR0     4104     // grid-barrier slots (single-use per launch, zeroed by k_init)
#define C_BAR1     4105
#define C_BAR2     4106
#define N_CTR_END  4160

#define GLIST_OFF  8192u    // uint2: all gated (f>=2) elements, (key, flat_idx)
#define CAPG       4194304u // expected ~380K; overflow -> fallback
#define LIST2_OFF  (GLIST_OFF + 2u*CAPG)
#define CAP2       4096u    // cutoff-bin candidates (expected ~190)
#define FB1_OFF    16777216u  // fallback scratch lists (correctness-only path)
#define CAPF       2097152u
#define FB2_OFF    (FB1_OFF + 2u*CAPF)

#define GBUF 1024           // per-token LDS staging for compaction

// Order-preserving fp32 -> u32 map (larger float <=> larger key)
__device__ __forceinline__ unsigned keyOf(float f) {
    unsigned b = __float_as_uint(f);
    return b ^ ((unsigned)((int)b >> 31) | 0x80000000u);
}
__device__ __forceinline__ float valOf(unsigned u) {
    unsigned b = (u & 0x80000000u) ? (u ^ 0x80000000u) : ~u;
    return __uint_as_float(b);
}
__device__ __forceinline__ unsigned umaxu(unsigned a, unsigned b) { return a > b ? a : b; }

// Device-scope grid barrier. Single-use slot per launch (no sense reversal needed);
// slot pre-zeroed by k_init. Writer side: __threadfence (agent release -> L2 WB) +
// device-scope atomicAdd. Reader side: relaxed spin + acquire fence (L1/L2 inv).
// Requires all gridDim.x blocks co-resident (guaranteed by launch config below).
__device__ __forceinline__ void gbar(unsigned* __restrict__ slot, unsigned nb) {
    __syncthreads();
    if (threadIdx.x == 0) {
        __threadfence();
        atomicAdd(slot, 1u);
        while (__hip_atomic_load(slot, __ATOMIC_RELAXED, __HIP_MEMORY_SCOPE_AGENT) < nb) {
            __builtin_amdgcn_s_sleep(2);
        }
        __threadfence();
    }
    __syncthreads();
}

// ---------------- init: zero fine bins + counters + barrier slots
__global__ void k_init(unsigned* __restrict__ ws) {
    int t = blockIdx.x * 256 + threadIdx.x;
    if (t < N_CTR_END) ws[t] = 0u;
}

// ---------------- fused pipeline: hist+zero+compact -> scan -> scatter -> tail.
// 256 threads/block, __launch_bounds__(256,4) => <=128 VGPR => 4 blocks/CU with
// 33.8 KB LDS (4*33.8=135 < 160 KB). grid = occ*numCU (<=1024) => fully co-resident.
__global__ __launch_bounds__(256, 4) void k_fused(const float4* __restrict__ x,
                                                  const int* __restrict__ mask,
                                                  const float* __restrict__ thr,
                                                  unsigned* __restrict__ ws,
                                                  float* __restrict__ out) {
    // Phase-overlaid LDS: P1 uses lh[4096]+sbuf[1024] (24.6 KB);
    // P2 uses sc[256]; P4 uses ent[4096 uint2]+red[256] (33.8 KB peak).
    __shared__ __align__(16) unsigned smem[8448];
    __shared__ unsigned s_cnt, s_base, s_b1, s_ka, s_found;
    const int tid = threadIdx.x;
    const unsigned nb = gridDim.x;
    const unsigned gtid = blockIdx.x * 256u + (unsigned)tid;
    const unsigned gstride = nb * 256u;

    // ---- P1: per-token fused {dense-zero, fine hist, gated compaction}
    unsigned* lh = smem;                        // [0, 4096)
    uint2* sbuf = (uint2*)(smem + NBINS);       // [4096, 6144) words
    for (int b = tid; b < NBINS; b += 256) lh[b] = 0u;   // accumulated over this block's tokens
    uint2* glist = (uint2*)(ws + GLIST_OFF);
    const float4 z = make_float4(0.f, 0.f, 0.f, 0.f);
    for (unsigned tok = blockIdx.x; tok < N_TOKENS; tok += nb) {
        float4* ot = (float4*)out + (size_t)tok * F4;
        if (!mask[tok]) {                       // masked token: zero output, no read
            for (int j = tid; j < F4; j += 256) ot[j] = z;
            continue;                           // mask uniform per block: no barrier divergence
        }
        if (tid == 0) s_cnt = 0u;
        __syncthreads();                        // also guards lh-zero before first atomics
        const float4* xt = x + (size_t)tok * F4;
        const unsigned baseIdx = (unsigned)tok * 16384u;
        for (int j = tid; j < F4; j += 512) {   // 2x unrolled: 2 loads + 2 stores in flight
            float4 v0 = xt[j];
            float4 v1 = xt[j + 256];
            ot[j] = z; ot[j + 256] = z;         // fused dense zero (winners overwritten later)
            float fv[8] = {v0.x, v0.y, v0.z, v0.w, v1.x, v1.y, v1.z, v1.w};
            #pragma unroll
            for (int c = 0; c < 8; ++c) {
                float f = fv[c];
                if (f >= 2.0f) {                // ~2.3% of elements; cutoff ~2.66 for this input
                    unsigned u = keyOf(f);
                    unsigned bin = (u - 0xC0000000u) >> 12;
                    if (bin > 4095u) bin = 4095u;       // f>=8 clamps to top bin
                    atomicAdd(&lh[bin], 1u);
                    unsigned slot = atomicAdd(&s_cnt, 1u);
                    unsigned idx = baseIdx + ((unsigned)(c < 4 ? j : j + 256)) * 4u + (unsigned)(c & 3);
                    uint2 e = make_uint2(u, idx);
                    if (slot < GBUF) sbuf[slot] = e;
                    else { unsigned g = atomicAdd(&ws[C_NG], 1u); if (g < CAPG) glist[g] = e; }
                }
            }
        }
        __syncthreads();
        unsigned cnt = s_cnt; if (cnt > GBUF) cnt = GBUF;   // expected ~373/token
        if (tid == 0) s_base = atomicAdd(&ws[C_NG], cnt);   // one bulk atomic/token
        __syncthreads();
        for (unsigned j2 = (unsigned)tid; j2 < cnt; j2 += 256u) {
            unsigned p = s_base + j2;
            if (p < CAPG) glist[p] = sbuf[j2];
        }
        __syncthreads();                        // protect sbuf reuse next token
    }
    __syncthreads();
    for (int b = tid; b < NBINS; b += 256) {    // merge block hist (2 tokens) once
        unsigned c = lh[b];
        if (c) atomicAdd(&ws[b], c);
    }
    gbar(&ws[C_BAR0], nb);

    // ---- P2: block 0 suffix-scans 4096 fine bins -> thresholds, need, fallback flag
    if (blockIdx.x == 0) {
        unsigned* sc = smem;                    // overlays lh (done with it)
        unsigned vv[16]; unsigned ssum = 0u;
        #pragma unroll
        for (int j = 0; j < 16; ++j) { vv[j] = ws[tid * 16 + j]; ssum += vv[j]; }
        if (tid == 0) s_found = 0u;
        sc[tid] = ssum;
        __syncthreads();
        for (int off = 1; off < 256; off <<= 1) {
            unsigned a = sc[tid];
            unsigned b2 = (tid + off < 256) ? sc[tid + off] : 0u;
            __syncthreads();
            sc[tid] = a + b2;                   // sc[t] = sum of partials [t..255]
            __syncthreads();
        }
        unsigned run = (tid < 255) ? sc[tid + 1] : 0u;      // cntGE(first bin of next chunk)
        #pragma unroll
        for (int j = 15; j >= 0; --j) {
            unsigned prev = run; run += vv[j];  // run = cntGE(bin tid*16+j)
            if (run >= K_TOTAL && prev < K_TOTAL) {          // unique crossing
                s_b1 = (unsigned)(tid * 16 + j); s_ka = prev; s_found = 1u;
            }
        }
        __syncthreads();
        if (tid == 0) {
            unsigned total = sc[0];
            unsigned ng = ws[C_NG];
            unsigned fb = (s_found == 0u) || (total < K_TOTAL) || (s_b1 == 4095u) || (ng > CAPG);
            ws[C_FB] = fb ? 1u : 0u;
            if (!fb) {
                unsigned candTh = 0xC0000000u + (s_b1 << 12);
                ws[C_CANDTH] = candTh;
                ws[C_WINTH]  = candTh + 0x1000u;
                ws[C_NEED]   = K_TOTAL - s_ka;
            }
        }
    }
    gbar(&ws[C_BAR1], nb);

    // ---- P3: scatter winners from the compact gated list (no x re-read)
    if (!ws[C_FB]) {
        const unsigned winTh = ws[C_WINTH], candTh = ws[C_CANDTH];
        unsigned ng = ws[C_NG]; if (ng > CAPG) ng = CAPG;
        uint2* list2 = (uint2*)(ws + LIST2_OFF);
        for (unsigned i = gtid; i < ng; i += gstride) {
            uint2 e = glist[i];
            if (e.x >= winTh) out[e.y] = valOf(e.x);         // >= 2.0 > 0: relu moot
            else if (e.x >= candTh) {                        // cutoff bin (~190 total)
                unsigned g = atomicAdd(&ws[C_N2], 1u);
                if (g < CAP2) list2[g] = e;
            }
        }
    }
    gbar(&ws[C_BAR2], nb);

    // ---- P4: block 0 exact rank among cutoff-bin candidates + EMA threshold
    if (blockIdx.x != 0) return;
    if (ws[C_FB]) return;
    unsigned rawn2 = ws[C_N2];
    if (rawn2 > CAP2) { if (tid == 0) ws[C_FB] = 1u; return; }   // hand off to fallback
    uint2* ent = (uint2*)smem;                  // [0, 8192) words
    unsigned* red = smem + 2u * CAP2;           // [8192, 8448)
    const unsigned n2 = rawn2;
    const unsigned need = ws[C_NEED];           // >= 1 by crossing construction
    uint2* list2 = (uint2*)(ws + LIST2_OFF);
    for (unsigned i = (unsigned)tid; i < n2; i += 256u) ent[i] = list2[i];
    __syncthreads();
    unsigned minSel = 0xFFFFFFFFu;
    for (unsigned i = (unsigned)tid; i < n2; i += 256u) {
        uint2 e = ent[i];
        unsigned rank = 0u;
        for (unsigned j = 0; j < n2; ++j) {     // ties -> lower idx (jax.lax.top_k)
            uint2 o = ent[j];
            rank += (o.x > e.x || (o.x == e.x && o.y < e.y)) ? 1u : 0u;
        }
        if (rank < need) {
            out[e.y] = valOf(e.x);
            if (e.x < minSel) minSel = e.x;
        }
    }
    red[tid] = minSel;
    __syncthreads();
    for (int off = 128; off > 0; off >>= 1) {
        if (tid < off) red[tid] = red[tid] < red[tid + off] ? red[tid] : red[tid + off];
        __syncthreads();
    }
    if (tid == 0) {
        // fast path: min selected = k-th largest >= 2.0 > 0 == min_pos
        out[N_ELEMS] = 0.99f * thr[0] + 0.01f * valOf(red[0]);
    }
}

// ---------------- fallback: full exact algorithm, single block (correctness-only;
// never runs for this input — cutoff >= 2.0 with 5.8x margin)
__global__ __launch_bounds__(1024) void k_fallback(const float4* __restrict__ x,
                                                   const int* __restrict__ mask,
                                                   unsigned* __restrict__ ws,
                                                   float* __restrict__ out,
                                                   const float* __restrict__ thr) {
    if (ws[C_FB] == 0u) return;
    __shared__ unsigned lh[NBINS];     // 16 KB, coarse 12-bit bins then reused
    __shared__ unsigned sred[1024];
    __shared__ unsigned sB1, sKA, sMode, sNegmin, sB2, sNeed, sCnt;
    const int t = threadIdx.x;
    for (int b = t; b < NBINS; b += 1024) lh[b] = 0u;
    __syncthreads();
    unsigned negmin = 0u;              // max(~key) over positive values
    for (int tok = 0; tok < N_TOKENS; ++tok) {
        if (!mask[tok]) continue;
        const float4* xt = x + (size_t)tok * F4;
        for (int j = t; j < F4; j += 1024) {
            float4 v = xt[j];
            float fv[4] = {v.x, v.y, v.z, v.w};
            #pragma unroll
            for (int c = 0; c < 4; ++c) {
                float f = fv[c];
                unsigned u = keyOf(f);
                atomicAdd(&lh[u >> 20], 1u);
                if (f > 0.0f) negmin = umaxu(negmin, ~u);
            }
        }
    }
    __syncthreads();
    sred[t] = negmin; __syncthreads();
    for (int off = 512; off > 0; off >>= 1) {
        if (t < off) sred[t] = umaxu(sred[t], sred[t + off]);
        __syncthreads();
    }
    if (t == 0) {
        sNegmin = sred[0];
        unsigned tot = 0u;
        for (int b = 0; b < NBINS; ++b) tot += lh[b];
        if (tot <= K_TOTAL) sMode = 1u;          // select ALL unmasked elements
        else {
            sMode = 0u;
            unsigned run = 0u, prev = 0u; int b1 = 0;
            for (int b = NBINS - 1; b >= 0; --b) {
                prev = run; run += lh[b];
                if (run >= K_TOTAL && prev < K_TOTAL) { b1 = b; break; }
            }
            sB1 = (unsigned)b1; sKA = prev;
        }
        sCnt = 0u;
    }
    __syncthreads();
    if (sMode == 1u) {
        for (int tok = 0; tok < N_TOKENS; ++tok) {
            if (!mask[tok]) continue;
            const float4* xt = x + (size_t)tok * F4;
            float* ot = out + (size_t)tok * 16384;
            for (int j = t; j < F4; j += 1024) {
                float4 v = xt[j];
                ot[j * 4 + 0] = fmaxf(v.x, 0.f); ot[j * 4 + 1] = fmaxf(v.y, 0.f);
                ot[j * 4 + 2] = fmaxf(v.z, 0.f); ot[j * 4 + 3] = fmaxf(v.w, 0.f);
            }
        }
        if (t == 0) {
            float th = thr[0], newt = th;
            if (sNegmin) newt = 0.99f * th + 0.01f * valOf(~sNegmin);
            out[N_ELEMS] = newt;
        }
        return;
    }
    // phase 2: scatter coarse winners; compact coarse cutoff bin
    const unsigned B1c = sB1;
    uint2* fb1 = (uint2*)(ws + FB1_OFF);
    for (int tok = 0; tok < N_TOKENS; ++tok) {
        if (!mask[tok]) continue;
        const float4* xt = x + (size_t)tok * F4;
        const unsigned baseIdx = (unsigned)tok * 16384u;
        for (int j = t; j < F4; j += 1024) {
            float4 v = xt[j];
            float fv[4] = {v.x, v.y, v.z, v.w};
            #pragma unroll
            for (int c = 0; c < 4; ++c) {
                float f = fv[c];
                unsigned u = keyOf(f);
                unsigned p = u >> 20;
                unsigned idx = baseIdx + (unsigned)j * 4u + (unsigned)c;
                if (p > B1c) out[idx] = fmaxf(f, 0.f);
                else if (p == B1c) {
                    unsigned g = atomicAdd(&sCnt, 1u);
                    if (g < CAPF) fb1[g] = make_uint2(u, idx);
                }
            }
        }
    }
    __syncthreads();
    unsigned n1 = sCnt > CAPF ? CAPF : sCnt;
    __syncthreads();
    if (t < 256) lh[t] = 0u;           // reuse as 8-bit refine histogram
    if (t == 0) sCnt = 0u;
    __syncthreads();
    for (unsigned i = t; i < n1; i += 1024)
        atomicAdd(&lh[(fb1[i].x >> 12) & 255u], 1u);
    __syncthreads();
    if (t == 0) {
        unsigned run = sKA, prev = sKA; int b2 = 0;
        for (int b = 255; b >= 0; --b) {
            prev = run; run += lh[b];
            if (run >= K_TOTAL) { b2 = b; break; }
        }
        sB2 = (unsigned)b2; sNeed = K_TOTAL - prev;
    }
    __syncthreads();
    const unsigned B2 = sB2, need = sNeed;
    uint2* fb2 = (uint2*)(ws + FB2_OFF);
    for (unsigned i = t; i < n1; i += 1024) {
        uint2 e = fb1[i];
        unsigned bb = (e.x >> 12) & 255u;
        if (bb > B2) out[e.y] = fmaxf(valOf(e.x), 0.f);
        else if (bb == B2) {
            unsigned g = atomicAdd(&sCnt, 1u);
            if (g < CAPF) fb2[g] = e;
        }
    }
    __syncthreads();
    unsigned n2 = sCnt > CAPF ? CAPF : sCnt;
    unsigned minSel = 0xFFFFFFFFu;
    for (unsigned i = t; i < n2; i += 1024) {
        uint2 e = fb2[i];
        unsigned rank = 0u;
        for (unsigned jj = 0; jj < n2; ++jj) {
            uint2 o = fb2[jj];
            rank += (o.x > e.x || (o.x == e.x && o.y < e.y)) ? 1u : 0u;
        }
        if (rank < need) { out[e.y] = fmaxf(valOf(e.x), 0.f); if (e.x < minSel) minSel = e.x; }
    }
    __syncthreads();
    sred[t] = minSel; __syncthreads();
    for (int off = 512; off > 0; off >>= 1) {
        if (t < off) sred[t] = sred[t] < sred[t + off] ? sred[t] : sred[t + off];
        __syncthreads();
    }
    if (t == 0) {
        float th = thr[0], newt = th;
        unsigned vku = sred[0];
        if (vku != 0xFFFFFFFFu) {
            float vk = valOf(vku);
            float minpos; int any;
            if (vk > 0.f) { minpos = vk; any = 1; }
            else { any = (sNegmin != 0u); minpos = any ? valOf(~sNegmin) : 0.f; }
            if (any) newt = 0.99f * th + 0.01f * minpos;
        }
        out[N_ELEMS] = newt;
    }
}

extern "C" void kernel_launch(void* const* d_in, const int* in_sizes, int n_in,
                              void* d_out, int out_size, void* d_ws, size_t ws_size,
                              hipStream_t stream) {
    const float4* x  = (const float4*)d_in[0];
    const int* mask  = (const int*)d_in[1];
    const float* thr = (const float*)d_in[2];
    float* out       = (float*)d_out;
    unsigned* ws     = (unsigned*)d_ws;

    // Co-resident grid sizing for the persistent kernel (cached; pure queries,
    // graph-capture-safe). LDS 33.8 KB + launch_bounds(256,4) => expect occ=4.
    static int grid_blocks = 0;
    if (grid_blocks == 0) {
        int occ = 0;
        if (hipOccupancyMaxActiveBlocksPerMultiprocessor(&occ, k_fused, 256, 0) != hipSuccess || occ < 1)
            occ = 1;
        if (occ > 4) occ = 4;               // LDS-derived hard cap: 4*33.8KB < 160KB
        int ncu = 256;
        int dev = 0;
        hipDeviceProp_t prop;
        if (hipGetDevice(&dev) == hipSuccess &&
            hipGetDeviceProperties(&prop, dev) == hipSuccess &&
            prop.multiProcessorCount > 0)
            ncu = prop.multiProcessorCount;
        long g = (long)occ * (long)ncu;
        if (g > 1024) g = 1024;
        if (g < 1) g = 1;
        grid_blocks = (int)g;
    }

    k_init    <<<17, 256, 0, stream>>>(ws);
    k_fused   <<<grid_blocks, 256, 0, stream>>>(x, mask, thr, ws, out);
    k_fallback<<<1, 1024, 0, stream>>>(x, mask, ws, out, thr);
}

// Round 2
// 267.017 us; speedup vs baseline: 2.4577x; 2.4577x over previous
//
#include <hip/hip_runtime.h>

// Problem constants (B=8, S=256, F=16384, K=32)
#define N_ELEMS  33554432   // 8*256*16384
#define N4       8388608    // N_ELEMS/4
#define N_TOKENS 2048
#define F4       4096       // float4 per token
#define K_TOTAL  65536u     // K * B * S
#define NBINS    4096       // fine bins over key range [0xC0000000, 0xC1000000) == f in [2,8)
                            // bin width ~0.001 at cutoff => ~190 elems in cutoff bin

// ws layout (uint32 word indices)
#define C_NG       4096     // gated-list counter
#define C_N2       4101     // cutoff-bin candidate counter
#define N_CTR_END  4160

#define GLIST_OFF  8192u    // uint2: all gated (f>=2) elements, (key, flat_idx)
#define CAPG       4194304u // expected ~380K; overflow -> fallback
#define LIST2_OFF  (GLIST_OFF + 2u*CAPG)
#define CAP2       4096u    // cutoff-bin candidates (expected ~190)
#define FB1_OFF    16777216u  // fallback scratch lists (correctness-only path)
#define CAPF       2097152u
#define FB2_OFF    (FB1_OFF + 2u*CAPF)

#define GBUF 1024           // per-block LDS staging for compaction

// Order-preserving fp32 -> u32 map (larger float <=> larger key)
__device__ __forceinline__ unsigned keyOf(float f) {
    unsigned b = __float_as_uint(f);
    return b ^ ((unsigned)((int)b >> 31) | 0x80000000u);
}
__device__ __forceinline__ float valOf(unsigned u) {
    unsigned b = (u & 0x80000000u) ? (u ^ 0x80000000u) : ~u;
    return __uint_as_float(b);
}
__device__ __forceinline__ unsigned umaxu(unsigned a, unsigned b) { return a > b ? a : b; }

// ---------------- init: zero fine bins + counters (no poison assumptions)
__global__ void k_init(unsigned* __restrict__ ws) {
    int t = blockIdx.x * 256 + threadIdx.x;
    if (t < N_CTR_END) ws[t] = 0u;
}

// ---------------- pass 1 (the ONLY full read of x): fine gated histogram
// + compact gated elements to global list + dense-zero this token's output.
// Inner loop restructured for MLP: 4 float4 loads issued back-to-back, 4 zero
// stores, THEN register processing (branchy insert path no longer serializes
// the load stream).
__global__ __launch_bounds__(512) void k_hist(const float4* __restrict__ x,
                                              const int* __restrict__ mask,
                                              unsigned* __restrict__ ws,
                                              float4* __restrict__ out) {
    __shared__ unsigned lh[NBINS];     // 16 KB
    __shared__ uint2 sbuf[GBUF];       // 8 KB staging for compaction
    __shared__ unsigned s_cnt, s_base;
    const int tok = blockIdx.x;
    const int tid = threadIdx.x;
    float4* ot = out + (size_t)tok * F4;
    const float4 z = make_float4(0.f, 0.f, 0.f, 0.f);
    if (!mask[tok]) {                  // masked token: zero output, no read
        for (int j = tid; j < F4; j += 512) ot[j] = z;
        return;
    }
    for (int b = tid; b < NBINS; b += 512) lh[b] = 0u;
    if (tid == 0) s_cnt = 0u;
    __syncthreads();
    uint2* glist = (uint2*)(ws + GLIST_OFF);
    const float4* xt = x + (size_t)tok * F4;
    const unsigned baseIdx = (unsigned)tok * 16384u;
    #pragma unroll
    for (int half = 0; half < 2; ++half) {       // 2 chunks of 4 float4/thread
        const int j0 = tid + half * 2048;
        float4 v0 = xt[j0];
        float4 v1 = xt[j0 + 512];
        float4 v2 = xt[j0 + 1024];
        float4 v3 = xt[j0 + 1536];
        ot[j0] = z; ot[j0 + 512] = z; ot[j0 + 1024] = z; ot[j0 + 1536] = z;
        float fv[16] = {v0.x, v0.y, v0.z, v0.w, v1.x, v1.y, v1.z, v1.w,
                        v2.x, v2.y, v2.z, v2.w, v3.x, v3.y, v3.z, v3.w};
        #pragma unroll
        for (int c = 0; c < 16; ++c) {
            float f = fv[c];
            if (f >= 2.0f) {           // ~2.3% of elements; cutoff ~2.66 for this input
                unsigned u = keyOf(f);
                unsigned bin = (u - 0xC0000000u) >> 12;
                if (bin > 4095u) bin = 4095u;      // f>=8 clamps to top bin
                atomicAdd(&lh[bin], 1u);
                unsigned slot = atomicAdd(&s_cnt, 1u);
                unsigned j = (unsigned)(j0 + (c >> 2) * 512);
                uint2 e = make_uint2(u, baseIdx + j * 4u + (unsigned)(c & 3));
                if (slot < GBUF) sbuf[slot] = e;
                else { unsigned g = atomicAdd(&ws[C_NG], 1u); if (g < CAPG) glist[g] = e; }
            }
        }
    }
    __syncthreads();
    for (int b = tid; b < NBINS; b += 512) {
        unsigned c = lh[b];
        if (c) atomicAdd(&ws[b], c);   // ~350 nonzero bins/block
    }
    unsigned cnt = s_cnt; if (cnt > GBUF) cnt = GBUF;   // expected ~373/block
    if (tid == 0) s_base = atomicAdd(&ws[C_NG], cnt);   // one bulk atomic/block
    __syncthreads();
    for (unsigned j = tid; j < cnt; j += 512) {
        unsigned p = s_base + j;
        if (p < CAPG) glist[p] = sbuf[j];
    }
}

// ---------------- scatter: each block REDUNDANTLY recomputes the suffix-scan
// (16 KB bin read + in-LDS scan, deterministic across blocks -> no k_scan1
// dispatch), then scatters winners from the compact gated list (no x re-read).
__global__ __launch_bounds__(256) void k_scatter(unsigned* __restrict__ ws,
                                                 float* __restrict__ out) {
    __shared__ unsigned sc[256];
    __shared__ unsigned s_b1, s_ka, s_found;
    const int t = threadIdx.x;
    unsigned vv[16];
    unsigned s = 0u;
    #pragma unroll
    for (int j = 0; j < 16; ++j) { vv[j] = ws[t * 16 + j]; s += vv[j]; }
    if (t == 0) { s_found = 0u; s_b1 = 0u; s_ka = 0u; }
    sc[t] = s;
    __syncthreads();
    for (int off = 1; off < 256; off <<= 1) {
        unsigned a = sc[t];
        unsigned b = (t + off < 256) ? sc[t + off] : 0u;
        __syncthreads();
        sc[t] = a + b;                 // sc[t] = cntGE(bin 16t)
        __syncthreads();
    }
    unsigned run = (t < 255) ? sc[t + 1] : 0u;   // cntGE(first bin of next chunk)
    #pragma unroll
    for (int j = 15; j >= 0; --j) {
        unsigned prev = run; run += vv[j];       // run = cntGE(bin 16t+j)
        if (run >= K_TOTAL && prev < K_TOTAL) {  // unique crossing
            s_b1 = (unsigned)(t * 16 + j); s_ka = prev; s_found = 1u;
        }
    }
    __syncthreads();
    const unsigned total = sc[0];
    unsigned ngRaw = ws[C_NG];
    if ((s_found == 0u) || (total < K_TOTAL) || (s_b1 == 4095u) || (ngRaw > CAPG))
        return;                        // fallback path (k_tail recomputes & handles)
    const unsigned candTh = 0xC0000000u + (s_b1 << 12);
    const unsigned winTh  = candTh + 0x1000u;
    unsigned ng = ngRaw;
    uint2* glist = (uint2*)(ws + GLIST_OFF);
    uint2* list2 = (uint2*)(ws + LIST2_OFF);
    const unsigned stride = gridDim.x * 256u;
    for (unsigned i = blockIdx.x * 256u + (unsigned)t; i < ng; i += stride) {
        uint2 e = glist[i];
        if (e.x >= winTh) out[e.y] = valOf(e.x);     // >= 2.0 > 0: relu moot
        else if (e.x >= candTh) {                    // cutoff bin (~190 total)
            unsigned g = atomicAdd(&ws[C_N2], 1u);
            if (g < CAP2) list2[g] = e;
        }
    }
}

// ---------------- tail + fallback merged (1 block, 1024 threads):
// recompute scan -> decide fast/fallback locally -> either exact rank among
// ~190 cutoff-bin candidates + EMA threshold, or the full exact algorithm.
__global__ __launch_bounds__(1024) void k_tail(const float4* __restrict__ x,
                                               const int* __restrict__ mask,
                                               unsigned* __restrict__ ws,
                                               float* __restrict__ out,
                                               const float* __restrict__ thr) {
    // LDS union: scan sc[1024] | tail ent[4096]uint2 + red[1024] | fb lh[4096]+sred[1024]
    __shared__ __align__(16) unsigned smem[9216];   // 36 KB
    __shared__ unsigned s_b1, s_ka, s_found, s_fb, s_need, s_n2;
    __shared__ unsigned sB1, sKA, sMode, sNegmin, sB2, sNeed, sCnt;
    const int t = threadIdx.x;

    { // ---- scan (identical math to the old k_scan1)
        unsigned* sc = smem;
        unsigned vv[4];
        unsigned s = 0u;
        #pragma unroll
        for (int j = 0; j < 4; ++j) { vv[j] = ws[t * 4 + j]; s += vv[j]; }
        if (t == 0) { s_found = 0u; s_b1 = 0u; s_ka = 0u; }
        sc[t] = s;
        __syncthreads();
        for (int off = 1; off < 1024; off <<= 1) {
            unsigned a = sc[t];
            unsigned b = (t + off < 1024) ? sc[t + off] : 0u;
            __syncthreads();
            sc[t] = a + b;
            __syncthreads();
        }
        unsigned run = (t < 1023) ? sc[t + 1] : 0u;
        #pragma unroll
        for (int j = 3; j >= 0; --j) {
            unsigned prev = run; run += vv[j];
            if (run >= K_TOTAL && prev < K_TOTAL) {
                s_b1 = (unsigned)(t * 4 + j); s_ka = prev; s_found = 1u;
            }
        }
        __syncthreads();
        if (t == 0) {
            unsigned total = sc[0];
            unsigned ng = ws[C_NG];
            unsigned n2v = ws[C_N2];
            unsigned fb = (s_found == 0u) || (total < K_TOTAL) || (s_b1 == 4095u) ||
                          (ng > CAPG) || (n2v > CAP2);
            s_fb = fb; s_need = K_TOTAL - s_ka; s_n2 = n2v;
        }
        __syncthreads();
    }

    if (!s_fb) {
        // ---- fast tail: exact rank among cutoff-bin candidates + EMA threshold
        uint2* ent = (uint2*)smem;                 // [0, 8192) words
        unsigned* red = smem + 8192;               // [8192, 9216)
        const unsigned n2 = s_n2;
        const unsigned need = s_need;              // >= 1 by crossing construction
        uint2* list2 = (uint2*)(ws + LIST2_OFF);
        for (unsigned i = (unsigned)t; i < n2; i += 1024u) ent[i] = list2[i];
        __syncthreads();
        unsigned minSel = 0xFFFFFFFFu;
        for (unsigned i = (unsigned)t; i < n2; i += 1024u) {
            uint2 e = ent[i];
            unsigned rank = 0u;
            for (unsigned j = 0; j < n2; ++j) {    // ties -> lower idx (jax.lax.top_k)
                uint2 o = ent[j];
                rank += (o.x > e.x || (o.x == e.x && o.y < e.y)) ? 1u : 0u;
            }
            if (rank < need) {
                out[e.y] = valOf(e.x);
                if (e.x < minSel) minSel = e.x;
            }
        }
        red[t] = minSel;
        __syncthreads();
        for (int off = 512; off > 0; off >>= 1) {
            if (t < off) red[t] = red[t] < red[t + off] ? red[t] : red[t + off];
            __syncthreads();
        }
        if (t == 0) {
            // fast path: min selected = k-th largest >= 2.0 > 0 == min_pos
            out[N_ELEMS] = 0.99f * thr[0] + 0.01f * valOf(red[0]);
        }
        return;
    }

    // ---- fallback: full exact algorithm (correctness-only; never runs for
    // this input — cutoff >= 2.0 with 5.8x margin)
    unsigned* lh = smem;               // [0, 4096): coarse 12-bit bins then reused
    unsigned* sred = smem + 4096;      // [4096, 5120)
    for (int b = t; b < NBINS; b += 1024) lh[b] = 0u;
    if (t == 0) sCnt = 0u;
    __syncthreads();
    unsigned negmin = 0u;              // max(~key) over positive values
    for (int tok = 0; tok < N_TOKENS; ++tok) {
        if (!mask[tok]) continue;
        const float4* xt = x + (size_t)tok * F4;
        for (int j = t; j < F4; j += 1024) {
            float4 v = xt[j];
            float fv[4] = {v.x, v.y, v.z, v.w};
            #pragma unroll
            for (int c = 0; c < 4; ++c) {
                float f = fv[c];
                unsigned u = keyOf(f);
                atomicAdd(&lh[u >> 20], 1u);
                if (f > 0.0f) negmin = umaxu(negmin, ~u);
            }
        }
    }
    __syncthreads();
    sred[t] = negmin; __syncthreads();
    for (int off = 512; off > 0; off >>= 1) {
        if (t < off) sred[t] = umaxu(sred[t], sred[t + off]);
        __syncthreads();
    }
    if (t == 0) {
        sNegmin = sred[0];
        unsigned tot = 0u;
        for (int b = 0; b < NBINS; ++b) tot += lh[b];
        if (tot <= K_TOTAL) sMode = 1u;          // select ALL unmasked elements
        else {
            sMode = 0u;
            unsigned run = 0u, prev = 0u; int b1 = 0;
            for (int b = NBINS - 1; b >= 0; --b) {
                prev = run; run += lh[b];
                if (run >= K_TOTAL && prev < K_TOTAL) { b1 = b; break; }
            }
            sB1 = (unsigned)b1; sKA = prev;
        }
        sCnt = 0u;
    }
    __syncthreads();
    if (sMode == 1u) {
        for (int tok = 0; tok < N_TOKENS; ++tok) {
            if (!mask[tok]) continue;
            const float4* xt = x + (size_t)tok * F4;
            float* ot = out + (size_t)tok * 16384;
            for (int j = t; j < F4; j += 1024) {
                float4 v = xt[j];
                ot[j * 4 + 0] = fmaxf(v.x, 0.f); ot[j * 4 + 1] = fmaxf(v.y, 0.f);
                ot[j * 4 + 2] = fmaxf(v.z, 0.f); ot[j * 4 + 3] = fmaxf(v.w, 0.f);
            }
        }
        if (t == 0) {
            float th = thr[0], newt = th;
            if (sNegmin) newt = 0.99f * th + 0.01f * valOf(~sNegmin);
            out[N_ELEMS] = newt;
        }
        return;
    }
    // phase 2: scatter coarse winners; compact coarse cutoff bin
    const unsigned B1c = sB1;
    uint2* fb1 = (uint2*)(ws + FB1_OFF);
    for (int tok = 0; tok < N_TOKENS; ++tok) {
        if (!mask[tok]) continue;
        const float4* xt = x + (size_t)tok * F4;
        const unsigned baseIdx = (unsigned)tok * 16384u;
        for (int j = t; j < F4; j += 1024) {
            float4 v = xt[j];
            float fv[4] = {v.x, v.y, v.z, v.w};
            #pragma unroll
            for (int c = 0; c < 4; ++c) {
                float f = fv[c];
                unsigned u = keyOf(f);
                unsigned p = u >> 20;
                unsigned idx = baseIdx + (unsigned)j * 4u + (unsigned)c;
                if (p > B1c) out[idx] = fmaxf(f, 0.f);
                else if (p == B1c) {
                    unsigned g = atomicAdd(&sCnt, 1u);
                    if (g < CAPF) fb1[g] = make_uint2(u, idx);
                }
            }
        }
    }
    __syncthreads();
    unsigned n1 = sCnt > CAPF ? CAPF : sCnt;
    __syncthreads();
    if (t < 256) lh[t] = 0u;           // reuse as 8-bit refine histogram
    if (t == 0) sCnt = 0u;
    __syncthreads();
    for (unsigned i = t; i < n1; i += 1024)
        atomicAdd(&lh[(fb1[i].x >> 12) & 255u], 1u);
    __syncthreads();
    if (t == 0) {
        unsigned run = sKA, prev = sKA; int b2 = 0;
        for (int b = 255; b >= 0; --b) {
            prev = run; run += lh[b];
            if (run >= K_TOTAL) { b2 = b; break; }
        }
        sB2 = (unsigned)b2; sNeed = K_TOTAL - prev;
    }
    __syncthreads();
    const unsigned B2 = sB2, need = sNeed;
    uint2* fb2 = (uint2*)(ws + FB2_OFF);
    for (unsigned i = t; i < n1; i += 1024) {
        uint2 e = fb1[i];
        unsigned bb = (e.x >> 12) & 255u;
        if (bb > B2) out[e.y] = fmaxf(valOf(e.x), 0.f);
        else if (bb == B2) {
            unsigned g = atomicAdd(&sCnt, 1u);
            if (g < CAPF) fb2[g] = e;
        }
    }
    __syncthreads();
    unsigned n2 = sCnt > CAPF ? CAPF : sCnt;
    unsigned minSel = 0xFFFFFFFFu;
    for (unsigned i = t; i < n2; i += 1024) {
        uint2 e = fb2[i];
        unsigned rank = 0u;
        for (unsigned jj = 0; jj < n2; ++jj) {
            uint2 o = fb2[jj];
            rank += (o.x > e.x || (o.x == e.x && o.y < e.y)) ? 1u : 0u;
        }
        if (rank < need) { out[e.y] = fmaxf(valOf(e.x), 0.f); if (e.x < minSel) minSel = e.x; }
    }
    __syncthreads();
    sred[t] = minSel; __syncthreads();
    for (int off = 512; off > 0; off >>= 1) {
        if (t < off) sred[t] = sred[t] < sred[t + off] ? sred[t] : sred[t + off];
        __syncthreads();
    }
    if (t == 0) {
        float th = thr[0], newt = th;
        unsigned vku = sred[0];
        if (vku != 0xFFFFFFFFu) {
            float vk = valOf(vku);
            float minpos; int any;
            if (vk > 0.f) { minpos = vk; any = 1; }
            else { any = (sNegmin != 0u); minpos = any ? valOf(~sNegmin) : 0.f; }
            if (any) newt = 0.99f * th + 0.01f * minpos;
        }
        out[N_ELEMS] = newt;
    }
}

extern "C" void kernel_launch(void* const* d_in, const int* in_sizes, int n_in,
                              void* d_out, int out_size, void* d_ws, size_t ws_size,
                              hipStream_t stream) {
    const float4* x  = (const float4*)d_in[0];
    const int* mask  = (const int*)d_in[1];
    const float* thr = (const float*)d_in[2];
    float* out       = (float*)d_out;
    unsigned* ws     = (unsigned*)d_ws;

    k_init    <<<17, 256, 0, stream>>>(ws);
    k_hist    <<<N_TOKENS, 512, 0, stream>>>(x, mask, ws, (float4*)out);
    k_scatter <<<512, 256, 0, stream>>>(ws, out);
    k_tail    <<<1, 1024, 0, stream>>>(x, mask, ws, out, thr);
}